// Round 2
// baseline (510.207 us; speedup 1.0000x reference)
//
#include <hip/hip_runtime.h>

#define NI 32
#define CI 128
#define HI 112
#define WI 112
#define OC 256
#define HO 110
#define WO 110

typedef float f32x16 __attribute__((ext_vector_type(16)));
typedef short s16x8 __attribute__((ext_vector_type(8)));

__device__ __forceinline__ ushort f2bf(float f) {
  union { float f; unsigned int u; } x; x.f = f;
  unsigned int r = x.u + 0x7FFFu + ((x.u >> 16) & 1u);
  return (ushort)(r >> 16);
}

// weight [oc][c][kh][kw] fp32 -> wp [kk=kh*3+kw][oc][c] bf16
__global__ __launch_bounds__(256) void pack_w_kernel(const float* __restrict__ w,
                                                     ushort* __restrict__ wp) {
  int i = blockIdx.x * 256 + threadIdx.x;  // 9*256*128 = 294912
  int c = i & 127;
  int rest = i >> 7;
  int oc = rest & 255;
  int kk = rest >> 8;  // 0..8
  int kh = kk / 3, kw = kk - kh * 3;
  wp[i] = f2bf(w[((oc * CI + c) * 3 + kh) * 3 + kw]);
}

// x [n][c][h][w] fp32 -> xn [n][h][w][c] bf16 (per-block: one (n,h) row, LDS transpose)
__global__ __launch_bounds__(256) void to_nhwc_kernel(const float* __restrict__ x,
                                                      ushort* __restrict__ xn) {
  __shared__ ushort lds[WI * CI];  // 14336 ushorts = 28 KB
  int b = blockIdx.x;              // n*112 + h
  int n = b / HI;
  int h = b - n * HI;
  const float* xr = x + ((size_t)n * CI * HI) * WI + (size_t)h * WI;  // + c*12544 + w
  int t = threadIdx.x;
  for (int i = t; i < WI * CI; i += 256) {
    int w = i >> 7, c = i & 127;                   // consecutive t -> consecutive c
    lds[i] = f2bf(xr[(size_t)c * (HI * WI) + w]);  // lds[w*128 + c]
  }
  __syncthreads();
  uint4* dst = (uint4*)(xn + (size_t)b * (WI * CI));
  const uint4* src = (const uint4*)lds;
  for (int i = t; i < (WI * CI) / 8; i += 256) dst[i] = src[i];
}

// Implicit GEMM, 32x32x16 MFMA. Block = (n, 2 output rows flattened to N=220 pixels)
// x 256 oc. A = weights (global/L2), B = staged input rows in XOR-swizzled LDS.
__global__ __launch_bounds__(512, 2) void conv_mfma_kernel(const ushort* __restrict__ xn,
                                                           const ushort* __restrict__ wp,
                                                           const float* __restrict__ bias,
                                                           float* __restrict__ out) {
  // 4 staged input rows [448 pix][128 c] bf16 = 114688 B, byte-XOR swizzled by ((pix&15)<<4)
  __shared__ ushort lds[448 * 128];
  const int bid = blockIdx.x;
  const int n = bid / 55;
  const int rp = bid - n * 55;
  const int oh0 = rp * 2;
  const int t = threadIdx.x;
  const int lane = t & 63;
  const int wid = t >> 6;
  const int col = lane & 31;
  const int colhi = lane >> 5;  // 0/1

  // ---- stage 4 input rows, LDS linear <- global pre-swizzled source ----
  const char* gsb = (const char*)(xn + ((size_t)n * HI + oh0) * (WI * CI));
  char* ldsb = (char*)lds;
  #pragma unroll
  for (int i = 0; i < 14; ++i) {
    int L = (i * 512 + t) * 16;
    int go = L ^ (((L >> 8) & 15) << 4);
    *(s16x8*)(ldsb + L) = *(const s16x8*)(gsb + go);
  }
  __syncthreads();

  const int ocq = wid & 3;  // SIMD id -> one np=0 and one np=1 wave per SIMD
  const int np = wid >> 2;  // pixel-fragment half: frags np*4 .. np*4+{3|2}
  const int oc0 = ocq * 64;

  // per-nf pixel decode (no kh/kw dependence)
  int prow[4], powc[4];
  #pragma unroll
  for (int nf = 0; nf < 4; ++nf) {
    int f = ((np * 4 + nf) << 5) + col;
    int fc = f > 219 ? 219 : f;
    int rr = fc >= 110;
    int ow = fc - 110 * rr;
    prow[nf] = rr;
    powc[nf] = ow;
  }

  f32x16 acc[2][4] = {};  // [mf: oc 32-frag][nf: pix 32-frag]

  const ushort* wlane = wp + (size_t)(oc0 + col) * CI + colhi * 8;
  #pragma unroll
  for (int kh = 0; kh < 3; ++kh) {
    #pragma unroll
    for (int kw = 0; kw < 3; ++kw) {
      const int kk = kh * 3 + kw;
      const ushort* wbase = wlane + (size_t)kk * (OC * CI);
      // per-nf swizzled row base for this (kh,kw)
      int pbase[4];
      #pragma unroll
      for (int nf = 0; nf < 4; ++nf) {
        int pix = (prow[nf] + kh) * WI + powc[nf] + kw;
        pbase[nf] = (pix << 8) | (((pix & 15) << 4) ^ (colhi << 4));
      }
      #pragma unroll
      for (int cstep = 0; cstep < 8; ++cstep) {  // K chunks of 16 channels
        s16x8 a[2];
        s16x8 b[4];
        #pragma unroll
        for (int mf = 0; mf < 2; ++mf)
          a[mf] = *(const s16x8*)(wbase + mf * 32 * CI + cstep * 16);
        #pragma unroll
        for (int nf = 0; nf < 4; ++nf)
          if (np * 4 + nf < 7)
            b[nf] = *(const s16x8*)(ldsb + (pbase[nf] ^ (cstep << 5)));
        __builtin_amdgcn_s_setprio(1);
        #pragma unroll
        for (int mf = 0; mf < 2; ++mf)
          #pragma unroll
          for (int nf = 0; nf < 4; ++nf)
            if (np * 4 + nf < 7)
              acc[mf][nf] = __builtin_amdgcn_mfma_f32_32x32x16_bf16(a[mf], b[nf],
                                                                    acc[mf][nf], 0, 0, 0);
        __builtin_amdgcn_s_setprio(0);
      }
    }
  }

  // ---- epilogue: D col=lane&31 -> flat pixel, row=(r&3)+8*(r>>2)+4*colhi -> oc ----
  #pragma unroll
  for (int mf = 0; mf < 2; ++mf) {
    #pragma unroll
    for (int nf = 0; nf < 4; ++nf) {
      if (np * 4 + nf < 7) {
        int f = ((np * 4 + nf) << 5) + col;
        if (f < 220) {
          int rr = f >= 110;
          int ow = f - 110 * rr;
          int oh = oh0 + rr;
          float* outb = out + ((size_t)n * OC + oc0 + mf * 32) * (HO * WO) +
                        (size_t)oh * WO + ow;
          #pragma unroll
          for (int r = 0; r < 16; ++r) {
            int ocr = (r & 3) + 8 * (r >> 2) + 4 * colhi;
            outb[(size_t)ocr * (HO * WO)] = acc[mf][nf][r] + bias[oc0 + mf * 32 + ocr];
          }
        }
      }
    }
  }
}

// Correctness fallback if ws is too small for the packed bf16 buffers.
__global__ __launch_bounds__(256) void conv_naive_kernel(const float* __restrict__ x,
                                                         const float* __restrict__ w,
                                                         const float* __restrict__ bias,
                                                         float* __restrict__ out) {
  long i = (long)blockIdx.x * 256 + threadIdx.x;
  const long total = (long)NI * OC * HO * WO;
  if (i >= total) return;
  int ow = (int)(i % WO);
  long r1 = i / WO;
  int oh = (int)(r1 % HO);
  long r2 = r1 / HO;
  int oc = (int)(r2 % OC);
  int n = (int)(r2 / OC);
  float s = bias[oc];
  const float* xb = x + ((size_t)n * CI * HI) * WI;
  const float* wb = w + (size_t)oc * CI * 9;
  for (int c = 0; c < CI; ++c)
    for (int kh = 0; kh < 3; ++kh)
      for (int kw = 0; kw < 3; ++kw)
        s += xb[((size_t)c * HI + oh + kh) * WI + ow + kw] * wb[(c * 3 + kh) * 3 + kw];
  out[i] = s;
}

extern "C" void kernel_launch(void* const* d_in, const int* in_sizes, int n_in,
                              void* d_out, int out_size, void* d_ws, size_t ws_size,
                              hipStream_t stream) {
  const float* x = (const float*)d_in[0];
  const float* w = (const float*)d_in[1];
  const float* bias = (const float*)d_in[2];
  float* out = (float*)d_out;

  const size_t xn_elems = (size_t)NI * HI * WI * CI;  // 51,380,224
  const size_t wp_elems = (size_t)9 * OC * CI;        // 294,912
  const size_t need = (xn_elems + wp_elems) * sizeof(ushort);

  if (ws_size >= need) {
    ushort* xnw = (ushort*)d_ws;
    ushort* wpw = xnw + xn_elems;
    hipLaunchKernelGGL(pack_w_kernel, dim3((unsigned)(wp_elems / 256)), dim3(256), 0, stream,
                       w, wpw);
    hipLaunchKernelGGL(to_nhwc_kernel, dim3(NI * HI), dim3(256), 0, stream, x, xnw);
    hipLaunchKernelGGL(conv_mfma_kernel, dim3(NI * 55), dim3(512), 0, stream, xnw, wpw, bias,
                       out);
  } else {
    long total = (long)NI * OC * HO * WO;
    hipLaunchKernelGGL(conv_naive_kernel, dim3((unsigned)((total + 255) / 256)), dim3(256), 0,
                       stream, x, w, bias, out);
  }
}